// Round 12
// baseline (262.663 us; speedup 1.0000x reference)
//
#include <hip/hip_runtime.h>
#include <hip/hip_bf16.h>
#include <stdint.h>

// Problem constants (from reference)
#define S_  32
#define P_  48
#define T_  8
#define E_  64
#define H_  64
#define D1_ 512
#define D2_ 1024
#define B_  (S_*P_)        // 1536
#define M_  (S_*P_*P_)     // 73728 rows of the big GEMMs
#define K1_ 576            // T*E + H
#define KE_ 512            // T*E

typedef __attribute__((ext_vector_type(8)))  short  short8;
typedef __attribute__((ext_vector_type(4)))  short  short4v;
typedef __attribute__((ext_vector_type(8)))  __bf16 bf16x8;
typedef __attribute__((ext_vector_type(4)))  float  f32x4;
typedef __attribute__((ext_vector_type(8)))  float  f32x8;
typedef __attribute__((ext_vector_type(16))) float  f32x16;

// fp32 -> bf16 (round to nearest even), bit carrier = short
__device__ inline short f2bf(float x) {
  union { float f; unsigned u; } v; v.f = x;
  unsigned r = v.u + 0x7FFFu + ((v.u >> 16) & 1u);
  return (short)(r >> 16);
}

// async global->LDS, 16 bytes per lane (wave-uniform LDS base + lane*16; the
// GLOBAL source address is per-lane -> T2 swizzle done by pre-swizzling source)
__device__ inline void async16(const void* g, void* l) {
  __builtin_amdgcn_global_load_lds(
      (const __attribute__((address_space(1))) void*)g,
      (__attribute__((address_space(3))) void*)l, 16, 0, 0);
}

__device__ inline f32x16 mfma32(short8 a, short8 b, f32x16 c) {
  return __builtin_amdgcn_mfma_f32_32x32x16_bf16(
      __builtin_bit_cast(bf16x8, a), __builtin_bit_cast(bf16x8, b), c, 0, 0, 0);
}

// ---------------------------------------------------------------- K0: weights -> bf16
__global__ __launch_bounds__(256) void k_cvt_w(const float* __restrict__ W1,
                                               const float* __restrict__ W2,
                                               short* __restrict__ W1b,
                                               short* __restrict__ W2b) {
  int idx = blockIdx.x * 256 + threadIdx.x;
  if (idx < D1_ * K1_) W1b[idx] = f2bf(W1[idx]);
  int idx2 = idx - D1_ * K1_;
  if (idx2 >= 0 && idx2 < D2_ * D1_) W2b[idx2] = f2bf(W2[idx2]);
}

// ---------------------------------------------------------------- K0b: oW[p][n] = obs[p] @ Wse^T  (fp32)
__global__ __launch_bounds__(256) void k_oW(const float* __restrict__ traj,
                                            const float* __restrict__ Wse,
                                            float* __restrict__ oW) {
  int bid = blockIdx.x;                 // 1536*2 blocks
  int p = bid >> 1;
  int n = ((bid & 1) << 8) + threadIdx.x;
  float obs[16];
#pragma unroll
  for (int t = 0; t < T_; ++t) {
    obs[2*t]   = traj[(t*B_ + p)*2 + 0];
    obs[2*t+1] = traj[(t*B_ + p)*2 + 1];
  }
  float acc = 0.f;
#pragma unroll
  for (int k = 0; k < 16; ++k) acc += obs[k] * Wse[n*16 + k];
  oW[p*KE_ + n] = acc;
}

// ---------------------------------------------------------------- K1: build X (bf16)
// X[row=(s,i,j)][n<512]  = tw[s,rem,n&1,n>>6] * (oW[bj][n] - oW[bi][n] + bse[n])
// X[row][n>=512]         = h[bj][n-512]
__global__ __launch_bounds__(256) void k_build_x(const float* __restrict__ tw,
                                                 const float* __restrict__ h,
                                                 const float* __restrict__ bse,
                                                 const float* __restrict__ oW,
                                                 short* __restrict__ X) {
  int tid = threadIdx.x;
  int wid = tid >> 6, lane = tid & 63;
  int row = blockIdx.x * 4 + wid;
  int s   = row / (P_ * P_);
  int rem = row - s * (P_ * P_);
  int i   = rem / P_;
  int j   = rem - i * P_;
  int bi = s * P_ + i, bj = s * P_ + j;

  const float* twq = tw + (size_t)(s * (P_*P_) + rem) * 16;  // [2][8]
  int t = lane >> 3;
  float w0 = twq[t];
  float w1 = twq[8 + t];

  int n0 = lane * 8;
  f32x8 vj = *(const f32x8*)&oW[(size_t)bj * KE_ + n0];
  f32x8 vi = *(const f32x8*)&oW[(size_t)bi * KE_ + n0];
  f32x8 vb = *(const f32x8*)&bse[n0];
  short8 o;
#pragma unroll
  for (int k = 0; k < 8; ++k) {
    float e = (vj[k] - vi[k] + vb[k]) * ((k & 1) ? w1 : w0);
    o[k] = f2bf(e);
  }
  *(short8*)&X[(size_t)row * K1_ + n0] = o;

  if (lane < 8) {
    f32x8 vh = *(const f32x8*)&h[(size_t)bj * H_ + lane * 8];
    short8 oh;
#pragma unroll
    for (int k = 0; k < 8; ++k) oh[k] = f2bf(vh[k]);
    *(short8*)&X[(size_t)row * K1_ + KE_ + lane * 8] = oh;
  }
}

// ---------------------------------------------------------------- K2: GEMM1 + relu (32x32x16 MFMA)
// X1 = relu(X[73728x576] @ W1b[512x576]^T + b1), bf16 out
// BM=192 BN=256 BK=64, 8 waves (2M x 4N), wave tile 96x64 = 3m x 2n frags.
// Grid 768 = 3.0 clean rounds @ 1 block/CU (112 KB LDS).
// SWAPPED operands: mfma32(b, a, acc) -> lane's C "col" = X row, C "row" =
// output col (consecutive by reg&3) -> short4 stores.
__global__ __launch_bounds__(512, 2) void k_gemm1(const short* __restrict__ X,
                                                  const short* __restrict__ W1b,
                                                  const float* __restrict__ b1,
                                                  short* __restrict__ X1) {
  __shared__ short Abuf[2][192 * 64];   //  48 KB
  __shared__ short Bbuf[2][256 * 64];   //  64 KB  (total 112 KB)
  int tid = threadIdx.x;
  int wid = tid >> 6, lane = tid & 63;
  // T1: grid 768 = 8 * 96
  int wgid = (blockIdx.x & 7) * 96 + (blockIdx.x >> 3);
  int tm = wgid >> 1, tn = wgid & 1;
  int brow = tm * 192, bcol = tn * 256;
  int wrm = wid >> 2, wcn = wid & 3;     // 2M x 4N
  int c31 = lane & 31, hi = lane >> 5;
  int sx = lane & 7;                     // row&7 == c31&7 == lane&7 (bases %8==0)

  f32x16 acc[3][2];
#pragma unroll
  for (int m = 0; m < 3; ++m)
#pragma unroll
    for (int n = 0; n < 2; ++n)
#pragma unroll
      for (int e = 0; e < 16; ++e) acc[m][n][e] = 0.f;

  auto stageA = [&](int buf, int k0) {   // 192x64 = 1536 granules / 512 thr
#pragma unroll
    for (int it = 0; it < 3; ++it) {
      int fg = it * 512 + tid;
      int r = fg >> 3, gs = (fg & 7) ^ (r & 7);
      async16(&X[(size_t)(brow + r) * K1_ + k0 + (gs << 3)], &Abuf[buf][fg * 8]);
    }
  };
  auto stageB = [&](int buf, int k0) {   // 256x64 = 2048 granules
#pragma unroll
    for (int it = 0; it < 4; ++it) {
      int fg = it * 512 + tid;
      int r = fg >> 3, gs = (fg & 7) ^ (r & 7);
      async16(&W1b[(size_t)(bcol + r) * K1_ + k0 + (gs << 3)], &Bbuf[buf][fg * 8]);
    }
  };
  auto compute = [&](int buf) {
#pragma unroll
    for (int ks = 0; ks < 4; ++ks) {     // K=16 per step
      int g = (2 * ks + hi) ^ sx;        // granule slot (8 bf16)
      short8 a[3], b[2];
#pragma unroll
      for (int m = 0; m < 3; ++m) {
        int row = wrm * 96 + m * 32 + c31;
        a[m] = *(const short8*)&Abuf[buf][row * 64 + (g << 3)];
      }
#pragma unroll
      for (int n = 0; n < 2; ++n) {
        int rowb = wcn * 64 + n * 32 + c31;
        b[n] = *(const short8*)&Bbuf[buf][rowb * 64 + (g << 3)];
      }
      __builtin_amdgcn_s_setprio(1);
#pragma unroll
      for (int m = 0; m < 3; ++m)
#pragma unroll
        for (int n = 0; n < 2; ++n)
          acc[m][n] = mfma32(b[n], a[m], acc[m][n]);   // SWAPPED
      __builtin_amdgcn_s_setprio(0);
    }
  };

  const int NT = 9;                      // K1_/64
  stageA(0, 0); stageB(0, 0);
  asm volatile("s_waitcnt vmcnt(0)" ::: "memory");
  __builtin_amdgcn_s_barrier();
  for (int t = 0; t < NT; ++t) {
    int bf = t & 1;
    if (t + 1 < NT) { stageA(bf ^ 1, (t + 1) * 64); stageB(bf ^ 1, (t + 1) * 64); }
    compute(bf);
    asm volatile("s_waitcnt vmcnt(0)" ::: "memory");
    __builtin_amdgcn_s_barrier();
  }

  // epilogue: row = brow+wrm*96+m*32+c31; col = bcol+wcn*64+n*32+8*rq+4*hi+e
#pragma unroll
  for (int m = 0; m < 3; ++m) {
    int grow = brow + wrm * 96 + m * 32 + c31;
#pragma unroll
    for (int n = 0; n < 2; ++n)
#pragma unroll
      for (int rq = 0; rq < 4; ++rq) {
        int colb = bcol + wcn * 64 + n * 32 + 8 * rq + 4 * hi;
        f32x4 bias = *(const f32x4*)&b1[colb];
        short4v o;
#pragma unroll
        for (int e = 0; e < 4; ++e) {
          float v = acc[m][n][rq * 4 + e] + bias[e];
          v = v > 0.f ? v : 0.f;
          o[e] = f2bf(v);
        }
        *(short4v*)&X1[(size_t)grow * D1_ + colb] = o;
      }
  }
}

// ---------------------------------------------------------------- K3: GEMM2 + relu + max over j (32x32x16)
// BM=192 (4 j-groups), BN=256, BK=64, 8 waves (2M x 4N), wave tile 96x64.
// Grid 1536 = 6.0 clean rounds. Unswapped mfma32(a,b,acc):
// C col = lane&31 (output col), C row = (reg&3)+8*(reg>>2)+4*hi (j-row).
// Wave rows 96 = 2 j-groups; group split inside frag m=1 at reg<8 / reg>=8.
__global__ __launch_bounds__(512, 2) void k_gemm2(const short* __restrict__ X1,
                                                  const short* __restrict__ W2b,
                                                  const float* __restrict__ b2,
                                                  float* __restrict__ out) {
  __shared__ short Abuf[2][192 * 64];   //  48 KB
  __shared__ short Bbuf[2][256 * 64];   //  64 KB  (total 112 KB)
  int tid = threadIdx.x;
  int wid = tid >> 6, lane = tid & 63;
  // T1: grid 1536 = 8 * 192
  int wgid = (blockIdx.x & 7) * 192 + (blockIdx.x >> 3);
  int tm = wgid >> 2, tn = wgid & 3;
  int brow = tm * 192, bcol = tn * 256;
  int wrm = wid >> 2, wcn = wid & 3;
  int c31 = lane & 31, hi = lane >> 5;
  int sx = lane & 7;

  f32x16 acc[3][2];
#pragma unroll
  for (int m = 0; m < 3; ++m)
#pragma unroll
    for (int n = 0; n < 2; ++n)
#pragma unroll
      for (int e = 0; e < 16; ++e) acc[m][n][e] = 0.f;

  auto stageA = [&](int buf, int k0) {
#pragma unroll
    for (int it = 0; it < 3; ++it) {
      int fg = it * 512 + tid;
      int r = fg >> 3, gs = (fg & 7) ^ (r & 7);
      async16(&X1[(size_t)(brow + r) * D1_ + k0 + (gs << 3)], &Abuf[buf][fg * 8]);
    }
  };
  auto stageB = [&](int buf, int k0) {
#pragma unroll
    for (int it = 0; it < 4; ++it) {
      int fg = it * 512 + tid;
      int r = fg >> 3, gs = (fg & 7) ^ (r & 7);
      async16(&W2b[(size_t)(bcol + r) * D1_ + k0 + (gs << 3)], &Bbuf[buf][fg * 8]);
    }
  };
  auto compute = [&](int buf) {
#pragma unroll
    for (int ks = 0; ks < 4; ++ks) {
      int g = (2 * ks + hi) ^ sx;
      short8 a[3], b[2];
#pragma unroll
      for (int m = 0; m < 3; ++m) {
        int row = wrm * 96 + m * 32 + c31;
        a[m] = *(const short8*)&Abuf[buf][row * 64 + (g << 3)];
      }
#pragma unroll
      for (int n = 0; n < 2; ++n) {
        int rowb = wcn * 64 + n * 32 + c31;
        b[n] = *(const short8*)&Bbuf[buf][rowb * 64 + (g << 3)];
      }
      __builtin_amdgcn_s_setprio(1);
#pragma unroll
      for (int m = 0; m < 3; ++m)
#pragma unroll
        for (int n = 0; n < 2; ++n)
          acc[m][n] = mfma32(a[m], b[n], acc[m][n]);   // unswapped
      __builtin_amdgcn_s_setprio(0);
    }
  };

  const int NT = 8;                      // D1_/64
  stageA(0, 0); stageB(0, 0);
  asm volatile("s_waitcnt vmcnt(0)" ::: "memory");
  __builtin_amdgcn_s_barrier();
  for (int t = 0; t < NT; ++t) {
    int bf = t & 1;
    if (t + 1 < NT) { stageA(bf ^ 1, (t + 1) * 64); stageB(bf ^ 1, (t + 1) * 64); }
    compute(bf);
    asm volatile("s_waitcnt vmcnt(0)" ::: "memory");
    __builtin_amdgcn_s_barrier();
  }

  // epilogue: groups g0 = rows 0-47 (m0 all + m1 reg<8),
  //           g1 = rows 48-95 (m1 reg>=8 + m2 all); shfl_xor(32) over hi.
  int gb = tm * 4 + wrm * 2;
#pragma unroll
  for (int n = 0; n < 2; ++n) {
    int gcol = bcol + wcn * 64 + n * 32 + c31;
    float bias = b2[gcol];
    float r0 = 0.f, r1 = 0.f;            // relu floor == identity for max(relu)
#pragma unroll
    for (int e = 0; e < 16; ++e) {
      float v0 = acc[0][n][e] + bias;
      float v1 = acc[2][n][e] + bias;
      float vm = acc[1][n][e] + bias;
      if (v0 > r0) r0 = v0;
      if (v1 > r1) r1 = v1;
      if (e < 8) { if (vm > r0) r0 = vm; }
      else       { if (vm > r1) r1 = vm; }
    }
    r0 = fmaxf(r0, __shfl_xor(r0, 32));
    r1 = fmaxf(r1, __shfl_xor(r1, 32));
    if (hi == 0) {
      out[(size_t)(gb    ) * D2_ + gcol] = r0;
      out[(size_t)(gb + 1) * D2_ + gcol] = r1;
    }
  }
}

// ----------------------------------------------------------------
extern "C" void kernel_launch(void* const* d_in, const int* in_sizes, int n_in,
                              void* d_out, int out_size, void* d_ws, size_t ws_size,
                              hipStream_t stream) {
  const float* h_states = (const float*)d_in[0];
  const float* traj = (const float*)d_in[3];
  const float* tw   = (const float*)d_in[4];
  const float* Wse  = (const float*)d_in[6];
  const float* bse  = (const float*)d_in[7];
  const float* W1   = (const float*)d_in[8];
  const float* b1   = (const float*)d_in[9];
  const float* W2   = (const float*)d_in[10];
  const float* b2   = (const float*)d_in[11];
  float* out = (float*)d_out;

  char* ws = (char*)d_ws;
  const size_t X_BYTES   = (size_t)M_ * K1_ * 2;   // 84,934,656
  const size_t X1_BYTES  = (size_t)M_ * D1_ * 2;   // 75,497,472
  const size_t W1B_BYTES = (size_t)D1_ * K1_ * 2;  //    589,824
  short* X   = (short*)ws;
  short* X1  = (short*)(ws + X_BYTES);
  short* W1b = (short*)(ws + X_BYTES + X1_BYTES);
  short* W2b = (short*)(ws + X_BYTES + X1_BYTES + W1B_BYTES);
  // oW (3 MB fp32) aliases head of X1: consumed by k_build_x before k_gemm1
  float* oW  = (float*)(ws + X_BYTES);

  k_cvt_w  <<<(D1_*K1_ + D2_*D1_ + 255) / 256, 256, 0, stream>>>(W1, W2, W1b, W2b);
  k_oW     <<<B_ * 2, 256, 0, stream>>>(traj, Wse, oW);
  k_build_x<<<M_ / 4, 256, 0, stream>>>(tw, h_states, bse, oW, X);
  k_gemm1  <<<(M_ / 192) * (D1_ / 256), 512, 0, stream>>>(X, W1b, b1, X1);
  k_gemm2  <<<(M_ / 192) * (D2_ / 256), 512, 0, stream>>>(X1, W2b, b2, out);
}